// Round 15
// baseline (1402.827 us; speedup 1.0000x reference)
//
#include <hip/hip_runtime.h>
#include <hip/hip_bf16.h>

typedef float f32x4 __attribute__((ext_vector_type(4)));
typedef __bf16 bf16x8 __attribute__((ext_vector_type(8)));
typedef unsigned short u16x8 __attribute__((ext_vector_type(8)));
typedef unsigned short u16;

__device__ __forceinline__ u16 f2bf(float f) {
  __bf16 h = (__bf16)f;                       // native cvt (RNE)
  return __builtin_bit_cast(u16, h);
}
__device__ __forceinline__ float bf2f(u16 s) {
  return __uint_as_float(((unsigned int)s) << 16);
}
__device__ __forceinline__ float gelu_f(float x) {
  return 0.5f * x * (1.0f + erff(x * 0.70710678118654752f)); // erf GELU
}
__device__ __forceinline__ void gload_lds16(const void* g, void* l) {
  __builtin_amdgcn_global_load_lds((const __attribute__((address_space(1))) void*)g,
                                   (__attribute__((address_space(3))) void*)l, 16, 0, 0);
}
#define MFMA(a, b, c) __builtin_amdgcn_mfma_f32_16x16x32_bf16((a), (b), (c), 0, 0, 0)
#define BARRIER_PINNED() do { \
    __builtin_amdgcn_s_barrier(); \
    asm volatile("" ::: "memory"); \
    __builtin_amdgcn_sched_barrier(0); \
  } while (0)

// ---------------- weight conversion ----------------
__global__ void cvt_all(const float* __restrict__ e1, const float* __restrict__ e2,
                        const float* __restrict__ e3, const float* __restrict__ d1,
                        const float* __restrict__ d2, const float* __restrict__ d3,
                        const float* __restrict__ mx, u16* __restrict__ dst)
{
  int i = blockIdx.x * blockDim.x + threadIdx.x;
  int stride = gridDim.x * blockDim.x;
  for (; i < 3145728; i += stride) {
    float v;
    if (i < 524288)        v = e1[i];
    else if (i < 786432)   v = e2[i - 524288];
    else if (i < 1048576)  v = e3[i - 786432];
    else if (i < 1310720)  v = d1[i - 1048576];
    else if (i < 1572864)  v = d2[i - 1310720];
    else if (i < 2097152)  v = d3[i - 1572864];
    else {
      // mix_w [L,16,16,32,32] (l,bi,j,e,d) -> W[l][o=bi*32+e][k=j*32+d]
      int j = i - 2097152;
      int l = j >> 18, rem = j & 262143;
      int o = rem >> 9, k = rem & 511;
      int bi = o >> 5, e = o & 31, jj = k >> 5, dd = k & 31;
      v = mx[(((l * 16 + bi) * 16 + jj) * 32 + e) * 32 + dd];
    }
    dst[i] = f2bf(v);
  }
}

// x f32 -> bf16 (vectorized)
__global__ void cvt_x(const float* __restrict__ s, u16* __restrict__ d) {
  int i = blockIdx.x * blockDim.x + threadIdx.x;
  int stride = gridDim.x * blockDim.x;
  for (; i < 8388608; i += stride) {
    float4 v0 = *(const float4*)(s + (size_t)i * 8);
    float4 v1 = *(const float4*)(s + (size_t)i * 8 + 4);
    u16x8 u;
    u[0] = f2bf(v0.x); u[1] = f2bf(v0.y); u[2] = f2bf(v0.z); u[3] = f2bf(v0.w);
    u[4] = f2bf(v1.x); u[5] = f2bf(v1.y); u[6] = f2bf(v1.z); u[7] = f2bf(v1.w);
    *(u16x8*)(d + (size_t)i * 8) = u;
  }
}

// ============ wide GEMM: BM=64, BN=512 (full weight width in LDS) ============
// Block = 512 thr (8 waves), owns 64 A-rows for ALL 512 cols (A read ONCE).
// LDS: A dbuf 2x8KB @0 | B dbuf 2x64KB @16384 -> 147456 B, 1 block/CU.
// Wave wid owns cols [wid*64, wid*64+64): acc[4][4] = 64 VGPR.
// Per K-tile: issue stage(kt+1) [1 A + 8 B gloads/thr] -> 32 MFMA/wave ->
// vmcnt(0) + barrier. B is L2-resident (shared by all blocks); A streams HBM.
// EPI: 0 bias+GELU->bf16 ; 1 bias->bf16 ; 2 latent combine->bf16 ; 3 bias->f32
template<int EPI>
__global__ __launch_bounds__(512, 2)
void gemm_wide(const u16* __restrict__ A, const u16* __restrict__ Bw,
               const float* __restrict__ bias, void* __restrict__ Cp,
               const u16* __restrict__ zOld, const float* __restrict__ scales,
               const float* __restrict__ gateBias, int N, int nOff, int K)
{
  extern __shared__ char smem[];
  const int tid = threadIdx.x;
  const int lane = tid & 63;
  const int wid = tid >> 6;
  const int m0 = blockIdx.x << 6;

  const int r16 = lane & 15;
  const int kg = (lane >> 4) << 3;          // k elem offset 0,8,16,24
  const int sw = (r16 & 7) << 4;            // XOR swizzle (row&7 == r16&7 here)

  const int NT = K >> 6;
  f32x4 acc[4][4] = {};

  // ---- stage one K-tile (A 64x64 = 8KB, B 512x64 = 64KB) into buffer b ----
  auto stage = [&](int kt, int b) {
    {
      int c = tid;                          // A: 1 chunk/thread (512 chunks)
      int row = c >> 3;
      int cb = (c & 7) << 4;
      const char* g = (const char*)(A + (size_t)(m0 + row) * K + (kt << 6))
                      + (cb ^ ((row & 7) << 4));
      gload_lds16(g, smem + (b << 13) + (wid << 10));
    }
    #pragma unroll
    for (int p = 0; p < 8; ++p) {           // B: 8 chunks/thread (4096 chunks)
      int c = (p << 9) + tid;
      int row = c >> 3;
      int cb = (c & 7) << 4;
      const char* g = (const char*)(Bw + (size_t)(nOff + row) * K + (kt << 6))
                      + (cb ^ ((row & 7) << 4));
      gload_lds16(g, smem + 16384 + (b << 16) + (((p << 3) + wid) << 10));
    }
  };

  stage(0, 0);
  asm volatile("s_waitcnt vmcnt(0)" ::: "memory");
  BARRIER_PINNED();

  for (int kt = 0; kt < NT; ++kt) {
    const int cur = kt & 1;
    if (kt + 1 < NT) stage(kt + 1, cur ^ 1);

    const char* Ac = smem + (cur << 13);
    const char* Bc = smem + 16384 + (cur << 16);
    #pragma unroll
    for (int kk = 0; kk < 64; kk += 32) {
      const int kb = ((kk + kg) << 1) ^ sw;
      bf16x8 av[4], bv[4];
      #pragma unroll
      for (int m = 0; m < 4; ++m)
        av[m] = *(const bf16x8*)(Ac + (m * 16 + r16) * 128 + kb);
      #pragma unroll
      for (int n = 0; n < 4; ++n)
        bv[n] = *(const bf16x8*)(Bc + ((wid << 6) + n * 16 + r16) * 128 + kb);
      __builtin_amdgcn_s_setprio(1);
      #pragma unroll
      for (int m = 0; m < 4; ++m)
        #pragma unroll
        for (int n = 0; n < 4; ++n)
          acc[m][n] = MFMA(av[m], bv[n], acc[m][n]);
      __builtin_amdgcn_s_setprio(0);
    }
    asm volatile("s_waitcnt vmcnt(0)" ::: "memory");
    BARRIER_PINNED();
  }

  // ---- epilogue ----  D: col = lane&15, row = (lane>>4)*4 + reg
  const int colBase = nOff + (wid << 6) + r16;
  const int rowBase = m0 + ((lane >> 4) << 2);
  #pragma unroll
  for (int n = 0; n < 4; ++n) {
    const int col = colBase + n * 16;
    float bv_ = 0.f, gate = 0.f;
    if constexpr (EPI == 0 || EPI == 1 || EPI == 3) bv_ = bias[col];
    if constexpr (EPI == 2) gate = 1.f / (1.f + expf(-gateBias[(col - nOff) >> 5]));
    #pragma unroll
    for (int m = 0; m < 4; ++m) {
      #pragma unroll
      for (int r = 0; r < 4; ++r) {
        const int row = rowBase + m * 16 + r;
        float v = acc[m][n][r];
        if constexpr (EPI == 0) {
          ((u16*)Cp)[(size_t)row * N + col] = f2bf(gelu_f(v + bv_));
        } else if constexpr (EPI == 1) {
          ((u16*)Cp)[(size_t)row * N + col] = f2bf(v + bv_);
        } else if constexpr (EPI == 2) {
          float sc = scales[(size_t)row * 16 + ((col - nOff) >> 5)];
          float zo = bf2f(zOld[(size_t)row * 512 + (col - nOff)]);
          ((u16*)Cp)[(size_t)row * N + col] = f2bf(zo * (1.f + sc) + gate * v);
        } else {
          ((float*)Cp)[(size_t)row * N + col] = v + bv_;
        }
      }
    }
  }
}

// ---------------- lane-per-row norm MLP ----------------
__global__ __launch_bounds__(256, 2)
void norm_mlp2(const u16* __restrict__ z,
               const float* __restrict__ w1, const float* __restrict__ b1,
               const float* __restrict__ w2, const float* __restrict__ b2,
               const float* __restrict__ w3, float* __restrict__ scales)
{
  __shared__ float nrm[256][17];
  const int tid = threadIdx.x;
  const size_t base = (size_t)blockIdx.x << 8;

  #pragma unroll
  for (int p = 0; p < 16; ++p) {
    const int C = (p << 8) + tid;
    const int r = C >> 4, b = C & 15;
    const u16* zp = z + ((base + r) << 9) + (b << 5);
    float ss = 0.f;
    #pragma unroll
    for (int q = 0; q < 4; ++q) {
      u16x8 v = *(const u16x8*)(zp + q * 8);
      #pragma unroll
      for (int j = 0; j < 8; ++j) { float f = bf2f(v[j]); ss += f * f; }
    }
    nrm[r][b] = sqrtf(ss) + 1e-8f;
  }
  __syncthreads();

  float nr[16];
  #pragma unroll
  for (int i = 0; i < 16; ++i) nr[i] = nrm[tid][i];

  float h2[64];
  #pragma unroll
  for (int j = 0; j < 64; ++j) h2[j] = b2[j];

  for (int kt = 0; kt < 4; ++kt) {
    float h1t[16];
    #pragma unroll
    for (int k16 = 0; k16 < 16; ++k16) {
      const int k = (kt << 4) + k16;
      float t = b1[k];
      #pragma unroll
      for (int i = 0; i < 16; ++i) t += nr[i] * w1[k * 16 + i];
      h1t[k16] = gelu_f(t);
    }
    const float* w2t = w2 + (kt << 4);
    #pragma unroll
    for (int j = 0; j < 64; ++j) {
      float s = 0.f;
      #pragma unroll
      for (int k16 = 0; k16 < 16; ++k16) s += h1t[k16] * w2t[j * 64 + k16];
      h2[j] += s;
    }
  }
  #pragma unroll
  for (int j = 0; j < 64; ++j) h2[j] = gelu_f(h2[j]);

  float* srow = scales + ((base + tid) << 4);
  #pragma unroll
  for (int b = 0; b < 16; ++b) {
    float s = 0.f;
    #pragma unroll
    for (int k = 0; k < 64; ++k) s += h2[k] * w3[b * 64 + k];
    s = (s > 20.f) ? s : log1pf(expf(s));
    srow[b] = s;
  }
}

// ---------------- launch ----------------
#define WIDE_SMEM 147456

extern "C" void kernel_launch(void* const* d_in, const int* in_sizes, int n_in,
                              void* d_out, int out_size, void* d_ws, size_t ws_size,
                              hipStream_t stream)
{
  (void)in_sizes; (void)n_in; (void)out_size; (void)ws_size;
  const float* x      = (const float*)d_in[0];
  const float* enc_w1 = (const float*)d_in[1];
  const float* enc_b1 = (const float*)d_in[2];
  const float* enc_w2 = (const float*)d_in[3];
  const float* enc_b2 = (const float*)d_in[4];
  const float* enc_w3 = (const float*)d_in[5];
  const float* enc_b3 = (const float*)d_in[6];
  const float* mlp1_w = (const float*)d_in[7];
  const float* mlp1_b = (const float*)d_in[8];
  const float* mlp2_w = (const float*)d_in[9];
  const float* mlp2_b = (const float*)d_in[10];
  const float* mlp3_w = (const float*)d_in[11];
  const float* mix_w  = (const float*)d_in[12];
  const float* gate_b = (const float*)d_in[13];
  const float* dec_w1 = (const float*)d_in[14];
  const float* dec_b1 = (const float*)d_in[15];
  const float* dec_w2 = (const float*)d_in[16];
  const float* dec_b2 = (const float*)d_in[17];
  const float* dec_w3 = (const float*)d_in[18];
  const float* dec_b3 = (const float*)d_in[19];

  char* ws = (char*)d_ws;
  const int M = 65536;

  // ws: xb 128MB | zA 64MB | (zB overlays xb) | scales 4MB | weights 6MB
  u16*   xb     = (u16*)ws;
  u16*   zA     = (u16*)(ws + 134217728ULL);
  u16*   zB     = (u16*)ws;                 // overlays xb (dead after enc1)
  float* scales = (float*)(ws + 201326592ULL);
  u16*   wBase  = (u16*)(ws + 205520896ULL);
  u16* wE1 = wBase;
  u16* wE2 = wE1 + 524288;
  u16* wE3 = wE2 + 262144;
  u16* wD1 = wE3 + 262144;
  u16* wD2 = wD1 + 262144;
  u16* wD3 = wD2 + 262144;
  u16* wMix = wD3 + 524288;

  hipError_t e;
  e = hipFuncSetAttribute(reinterpret_cast<const void*>(&gemm_wide<0>),
                          hipFuncAttributeMaxDynamicSharedMemorySize, WIDE_SMEM);
  e = hipFuncSetAttribute(reinterpret_cast<const void*>(&gemm_wide<1>),
                          hipFuncAttributeMaxDynamicSharedMemorySize, WIDE_SMEM);
  e = hipFuncSetAttribute(reinterpret_cast<const void*>(&gemm_wide<2>),
                          hipFuncAttributeMaxDynamicSharedMemorySize, WIDE_SMEM);
  e = hipFuncSetAttribute(reinterpret_cast<const void*>(&gemm_wide<3>),
                          hipFuncAttributeMaxDynamicSharedMemorySize, WIDE_SMEM);
  (void)e;

  cvt_all<<<512, 256, 0, stream>>>(enc_w1, enc_w2, enc_w3, dec_w1, dec_w2, dec_w3,
                                   mix_w, wBase);

  dim3 blk(512);
  const int grid = 1024;                    // M/64 blocks

  // encoder
  cvt_x<<<2048, 256, 0, stream>>>(x, xb);
  gemm_wide<0><<<grid, blk, WIDE_SMEM, stream>>>(xb, wE1, enc_b1, zA, nullptr, nullptr, nullptr, 512, 0, 1024);
  gemm_wide<0><<<grid, blk, WIDE_SMEM, stream>>>(zA, wE2, enc_b2, zB, nullptr, nullptr, nullptr, 512, 0, 512);
  gemm_wide<1><<<grid, blk, WIDE_SMEM, stream>>>(zB, wE3, enc_b3, zA, nullptr, nullptr, nullptr, 512, 0, 512);

  // latent layers
  u16* cur = zA;
  u16* nxt = zB;
  for (int l = 0; l < 4; ++l) {
    norm_mlp2<<<256, dim3(256), 0, stream>>>(cur, mlp1_w + l * 1024, mlp1_b + l * 64,
                                             mlp2_w + l * 4096, mlp2_b + l * 64,
                                             mlp3_w + l * 1024, scales);
    gemm_wide<2><<<grid, blk, WIDE_SMEM, stream>>>(cur, wMix + (size_t)l * 262144, nullptr, nxt,
                                                   cur, scales, gate_b + l * 16, 512, 0, 512);
    u16* t = cur; cur = nxt; nxt = t;
  }

  // decoder
  gemm_wide<0><<<grid, blk, WIDE_SMEM, stream>>>(cur, wD1, dec_b1, nxt, nullptr, nullptr, nullptr, 512, 0, 512);
  { u16* t = cur; cur = nxt; nxt = t; }
  gemm_wide<0><<<grid, blk, WIDE_SMEM, stream>>>(cur, wD2, dec_b2, nxt, nullptr, nullptr, nullptr, 512, 0, 512);
  { u16* t = cur; cur = nxt; nxt = t; }
  gemm_wide<3><<<grid, blk, WIDE_SMEM, stream>>>(cur, wD3, dec_b3, d_out, nullptr, nullptr, nullptr, 1024, 0, 512);
  gemm_wide<3><<<grid, blk, WIDE_SMEM, stream>>>(cur, wD3, dec_b3, d_out, nullptr, nullptr, nullptr, 1024, 512, 512);
}

// Round 16
// 1198.974 us; speedup vs baseline: 1.1700x; 1.1700x over previous
//
#include <hip/hip_runtime.h>
#include <hip/hip_bf16.h>

typedef float f32x4 __attribute__((ext_vector_type(4)));
typedef __bf16 bf16x8 __attribute__((ext_vector_type(8)));
typedef unsigned short u16x8 __attribute__((ext_vector_type(8)));
typedef unsigned short u16;

__device__ __forceinline__ u16 f2bf(float f) {
  __bf16 h = (__bf16)f;                       // native cvt (RNE)
  return __builtin_bit_cast(u16, h);
}
__device__ __forceinline__ float bf2f(u16 s) {
  return __uint_as_float(((unsigned int)s) << 16);
}
__device__ __forceinline__ float gelu_f(float x) {
  return 0.5f * x * (1.0f + erff(x * 0.70710678118654752f)); // erf GELU
}
__device__ __forceinline__ void gload_lds16(const void* g, void* l) {
  __builtin_amdgcn_global_load_lds((const __attribute__((address_space(1))) void*)g,
                                   (__attribute__((address_space(3))) void*)l, 16, 0, 0);
}
#define MFMA(a, b, c) __builtin_amdgcn_mfma_f32_16x16x32_bf16((a), (b), (c), 0, 0, 0)
#define BARRIER_PINNED() do { \
    __builtin_amdgcn_s_barrier(); \
    asm volatile("" ::: "memory"); \
    __builtin_amdgcn_sched_barrier(0); \
  } while (0)

// ---------------- weight conversion ----------------
__global__ void cvt_all(const float* __restrict__ e1, const float* __restrict__ e2,
                        const float* __restrict__ e3, const float* __restrict__ d1,
                        const float* __restrict__ d2, const float* __restrict__ d3,
                        const float* __restrict__ mx, u16* __restrict__ dst)
{
  int i = blockIdx.x * blockDim.x + threadIdx.x;
  int stride = gridDim.x * blockDim.x;
  for (; i < 3145728; i += stride) {
    float v;
    if (i < 524288)        v = e1[i];
    else if (i < 786432)   v = e2[i - 524288];
    else if (i < 1048576)  v = e3[i - 786432];
    else if (i < 1310720)  v = d1[i - 1048576];
    else if (i < 1572864)  v = d2[i - 1310720];
    else if (i < 2097152)  v = d3[i - 1572864];
    else {
      // mix_w [L,16,16,32,32] (l,bi,j,e,d) -> W[l][o=bi*32+e][k=j*32+d]
      int j = i - 2097152;
      int l = j >> 18, rem = j & 262143;
      int o = rem >> 9, k = rem & 511;
      int bi = o >> 5, e = o & 31, jj = k >> 5, dd = k & 31;
      v = mx[(((l * 16 + bi) * 16 + jj) * 32 + e) * 32 + dd];
    }
    dst[i] = f2bf(v);
  }
}

// x f32 -> bf16 (vectorized)
__global__ void cvt_x(const float* __restrict__ s, u16* __restrict__ d) {
  int i = blockIdx.x * blockDim.x + threadIdx.x;
  int stride = gridDim.x * blockDim.x;
  for (; i < 8388608; i += stride) {
    float4 v0 = *(const float4*)(s + (size_t)i * 8);
    float4 v1 = *(const float4*)(s + (size_t)i * 8 + 4);
    u16x8 u;
    u[0] = f2bf(v0.x); u[1] = f2bf(v0.y); u[2] = f2bf(v0.z); u[3] = f2bf(v0.w);
    u[4] = f2bf(v1.x); u[5] = f2bf(v1.y); u[6] = f2bf(v1.z); u[7] = f2bf(v1.w);
    *(u16x8*)(d + (size_t)i * 8) = u;
  }
}

// ============ big-tile pipelined GEMM: BM=256, BN=128, BK=64 ============
// 512 thr (8 waves 2Mx4N), wave tile 128x32: acc[8][2]=64 (AGPR side).
// LDS: 3-buffer ring x (A 32KB + B 16KB) = 144KB, 1 block/CU.
// r12-verified control flow: wait vmcnt(6) at TOP (tile kt's 6 loads done;
// issued 2 iterations ago) -> barrier -> issue tile kt+2 -> 32 MFMA/wave.
// Per-thread global pointers hoisted (rowA/rowB fixed per thread).
// EPI: 0 bias+GELU->bf16 ; 1 bias->bf16 ; 2 latent combine->bf16 ; 3 bias->f32
template<int EPI>
__global__ __launch_bounds__(512, 2)
void gemm_big(const u16* __restrict__ A, const u16* __restrict__ Bw,
              const float* __restrict__ bias, void* __restrict__ Cp,
              const u16* __restrict__ zOld, const float* __restrict__ scales,
              const float* __restrict__ gateBias, int M, int N, int K)
{
  extern __shared__ char smem[];             // 3 x 49152 (A@0, B@32768 per buf)
  const int tid = threadIdx.x;
  const int lane = tid & 63;
  const int wid = tid >> 6;

  // XCD-aware bijective swizzle (ny = M/256 = 256, ny%8==0)
  const int nx = N >> 7;
  const int ny = M >> 8;
  const int d = blockIdx.x;
  const int xcd = d & 7;
  const int seq = d >> 3;
  const int by = xcd * (ny >> 3) + seq / nx;
  const int bx = seq - (seq / nx) * nx;
  const int m0 = by << 8;
  const int n0 = bx << 7;

  const int wr = wid >> 2;                   // 0..1: M half (128 rows)
  const int wc = wid & 3;                    // 0..3: N quarter (32 cols)
  const int r16 = lane & 15;
  const int kg = (lane >> 4) << 3;
  const int sw = (r16 & 7) << 4;

  // hoisted per-thread staging pointers (element units; +kt*64 per tile)
  const u16* pA[4];
  const u16* pB[2];
  #pragma unroll
  for (int it = 0; it < 4; ++it) {
    int c = ((it * 8 + wid) << 6) + lane;    // A chunk id [0,2048)
    int row = c >> 3;
    int cb = (c & 7) << 4;
    pA[it] = A + (size_t)(m0 + row) * K + ((cb ^ ((row & 7) << 4)) >> 1);
  }
  #pragma unroll
  for (int it = 0; it < 2; ++it) {
    int c = ((it * 8 + wid) << 6) + lane;    // B chunk id [0,1024)
    int row = c >> 3;
    int cb = (c & 7) << 4;
    pB[it] = Bw + (size_t)(n0 + row) * K + ((cb ^ ((row & 7) << 4)) >> 1);
  }

  auto stage = [&](int kt, int b) {
    char* dstA = smem + b * 49152;
    char* dstB = dstA + 32768;
    const int ko = kt << 6;
    #pragma unroll
    for (int it = 0; it < 4; ++it)
      gload_lds16(pA[it] + ko, dstA + ((it * 8 + wid) << 10));
    #pragma unroll
    for (int it = 0; it < 2; ++it)
      gload_lds16(pB[it] + ko, dstB + ((it * 8 + wid) << 10));
  };

  const int NT = K >> 6;
  f32x4 acc[8][2] = {};

  stage(0, 0);
  stage(1, 1);

  int cb = 0, ib = 2;
  for (int kt = 0; kt < NT; ++kt) {
    if (kt + 1 < NT) { asm volatile("s_waitcnt vmcnt(6)" ::: "memory"); }
    else             { asm volatile("s_waitcnt vmcnt(0)" ::: "memory"); }
    BARRIER_PINNED();

    if (kt + 2 < NT) {
      stage(kt + 2, ib);
      ib = (ib == 2) ? 0 : ib + 1;
    }

    const char* Ac = smem + cb * 49152;
    const char* Bc = Ac + 32768;
    #pragma unroll
    for (int kk = 0; kk < 64; kk += 32) {
      const int kb = ((kk + kg) << 1) ^ sw;
      bf16x8 bv0 = *(const bf16x8*)(Bc + ((wc * 32 + r16) << 7) + kb);
      bf16x8 bv1 = *(const bf16x8*)(Bc + ((wc * 32 + 16 + r16) << 7) + kb);
      #pragma unroll
      for (int mh = 0; mh < 2; ++mh) {       // m-half batching keeps VGPR low
        bf16x8 av[4];
        #pragma unroll
        for (int m = 0; m < 4; ++m)
          av[m] = *(const bf16x8*)(Ac + ((wr * 128 + mh * 64 + m * 16 + r16) << 7) + kb);
        __builtin_amdgcn_s_setprio(1);
        #pragma unroll
        for (int m = 0; m < 4; ++m) {
          acc[mh * 4 + m][0] = MFMA(av[m], bv0, acc[mh * 4 + m][0]);
          acc[mh * 4 + m][1] = MFMA(av[m], bv1, acc[mh * 4 + m][1]);
        }
        __builtin_amdgcn_s_setprio(0);
      }
    }
    cb = (cb == 2) ? 0 : cb + 1;
  }

  // ---- epilogue ----  D: col = lane&15, row = (lane>>4)*4 + reg
  const int colBase = n0 + wc * 32 + r16;
  const int rowBase = m0 + wr * 128 + ((lane >> 4) << 2);
  #pragma unroll
  for (int n = 0; n < 2; ++n) {
    const int col = colBase + n * 16;
    float bv_ = 0.f, gate = 0.f;
    if constexpr (EPI == 0 || EPI == 1 || EPI == 3) bv_ = bias[col];
    if constexpr (EPI == 2) gate = 1.f / (1.f + expf(-gateBias[col >> 5]));
    #pragma unroll
    for (int m = 0; m < 8; ++m) {
      #pragma unroll
      for (int r = 0; r < 4; ++r) {
        const int row = rowBase + m * 16 + r;
        float v = acc[m][n][r];
        if constexpr (EPI == 0) {
          ((u16*)Cp)[(size_t)row * N + col] = f2bf(gelu_f(v + bv_));
        } else if constexpr (EPI == 1) {
          ((u16*)Cp)[(size_t)row * N + col] = f2bf(v + bv_);
        } else if constexpr (EPI == 2) {
          float sc = scales[(size_t)row * 16 + (col >> 5)];
          float zo = bf2f(zOld[(size_t)row * 512 + col]);
          ((u16*)Cp)[(size_t)row * N + col] = f2bf(zo * (1.f + sc) + gate * v);
        } else {
          ((float*)Cp)[(size_t)row * N + col] = v + bv_;
        }
      }
    }
  }
}

// ---------------- lane-per-row norm MLP ----------------
__global__ __launch_bounds__(256, 2)
void norm_mlp2(const u16* __restrict__ z,
               const float* __restrict__ w1, const float* __restrict__ b1,
               const float* __restrict__ w2, const float* __restrict__ b2,
               const float* __restrict__ w3, float* __restrict__ scales)
{
  __shared__ float nrm[256][17];
  const int tid = threadIdx.x;
  const size_t base = (size_t)blockIdx.x << 8;

  #pragma unroll
  for (int p = 0; p < 16; ++p) {
    const int C = (p << 8) + tid;
    const int r = C >> 4, b = C & 15;
    const u16* zp = z + ((base + r) << 9) + (b << 5);
    float ss = 0.f;
    #pragma unroll
    for (int q = 0; q < 4; ++q) {
      u16x8 v = *(const u16x8*)(zp + q * 8);
      #pragma unroll
      for (int j = 0; j < 8; ++j) { float f = bf2f(v[j]); ss += f * f; }
    }
    nrm[r][b] = sqrtf(ss) + 1e-8f;
  }
  __syncthreads();

  float nr[16];
  #pragma unroll
  for (int i = 0; i < 16; ++i) nr[i] = nrm[tid][i];

  float h2[64];
  #pragma unroll
  for (int j = 0; j < 64; ++j) h2[j] = b2[j];

  for (int kt = 0; kt < 4; ++kt) {
    float h1t[16];
    #pragma unroll
    for (int k16 = 0; k16 < 16; ++k16) {
      const int k = (kt << 4) + k16;
      float t = b1[k];
      #pragma unroll
      for (int i = 0; i < 16; ++i) t += nr[i] * w1[k * 16 + i];
      h1t[k16] = gelu_f(t);
    }
    const float* w2t = w2 + (kt << 4);
    #pragma unroll
    for (int j = 0; j < 64; ++j) {
      float s = 0.f;
      #pragma unroll
      for (int k16 = 0; k16 < 16; ++k16) s += h1t[k16] * w2t[j * 64 + k16];
      h2[j] += s;
    }
  }
  #pragma unroll
  for (int j = 0; j < 64; ++j) h2[j] = gelu_f(h2[j]);

  float* srow = scales + ((base + tid) << 4);
  #pragma unroll
  for (int b = 0; b < 16; ++b) {
    float s = 0.f;
    #pragma unroll
    for (int k = 0; k < 64; ++k) s += h2[k] * w3[b * 64 + k];
    s = (s > 20.f) ? s : log1pf(expf(s));
    srow[b] = s;
  }
}

// ---------------- launch ----------------
#define BIG_SMEM 147456

extern "C" void kernel_launch(void* const* d_in, const int* in_sizes, int n_in,
                              void* d_out, int out_size, void* d_ws, size_t ws_size,
                              hipStream_t stream)
{
  (void)in_sizes; (void)n_in; (void)out_size; (void)ws_size;
  const float* x      = (const float*)d_in[0];
  const float* enc_w1 = (const float*)d_in[1];
  const float* enc_b1 = (const float*)d_in[2];
  const float* enc_w2 = (const float*)d_in[3];
  const float* enc_b2 = (const float*)d_in[4];
  const float* enc_w3 = (const float*)d_in[5];
  const float* enc_b3 = (const float*)d_in[6];
  const float* mlp1_w = (const float*)d_in[7];
  const float* mlp1_b = (const float*)d_in[8];
  const float* mlp2_w = (const float*)d_in[9];
  const float* mlp2_b = (const float*)d_in[10];
  const float* mlp3_w = (const float*)d_in[11];
  const float* mix_w  = (const float*)d_in[12];
  const float* gate_b = (const float*)d_in[13];
  const float* dec_w1 = (const float*)d_in[14];
  const float* dec_b1 = (const float*)d_in[15];
  const float* dec_w2 = (const float*)d_in[16];
  const float* dec_b2 = (const float*)d_in[17];
  const float* dec_w3 = (const float*)d_in[18];
  const float* dec_b3 = (const float*)d_in[19];

  char* ws = (char*)d_ws;
  const int M = 65536;

  // ws: xb 128MB | zA 64MB | (zB overlays xb) | scales 4MB | weights 6MB
  u16*   xb     = (u16*)ws;
  u16*   zA     = (u16*)(ws + 134217728ULL);
  u16*   zB     = (u16*)ws;                 // overlays xb (dead after enc1)
  float* scales = (float*)(ws + 201326592ULL);
  u16*   wBase  = (u16*)(ws + 205520896ULL);
  u16* wE1 = wBase;
  u16* wE2 = wE1 + 524288;
  u16* wE3 = wE2 + 262144;
  u16* wD1 = wE3 + 262144;
  u16* wD2 = wD1 + 262144;
  u16* wD3 = wD2 + 262144;
  u16* wMix = wD3 + 524288;

  hipError_t e;
  e = hipFuncSetAttribute(reinterpret_cast<const void*>(&gemm_big<0>),
                          hipFuncAttributeMaxDynamicSharedMemorySize, BIG_SMEM);
  e = hipFuncSetAttribute(reinterpret_cast<const void*>(&gemm_big<1>),
                          hipFuncAttributeMaxDynamicSharedMemorySize, BIG_SMEM);
  e = hipFuncSetAttribute(reinterpret_cast<const void*>(&gemm_big<2>),
                          hipFuncAttributeMaxDynamicSharedMemorySize, BIG_SMEM);
  e = hipFuncSetAttribute(reinterpret_cast<const void*>(&gemm_big<3>),
                          hipFuncAttributeMaxDynamicSharedMemorySize, BIG_SMEM);
  (void)e;

  cvt_all<<<512, 256, 0, stream>>>(enc_w1, enc_w2, enc_w3, dec_w1, dec_w2, dec_w3,
                                   mix_w, wBase);

  dim3 blk(512);
  const int g512  = 256 * 4;                // (M/256)*(N/128), XCD-swizzled
  const int g1024 = 256 * 8;

  // encoder
  cvt_x<<<2048, 256, 0, stream>>>(x, xb);
  gemm_big<0><<<g512, blk, BIG_SMEM, stream>>>(xb, wE1, enc_b1, zA, nullptr, nullptr, nullptr, M, 512, 1024);
  gemm_big<0><<<g512, blk, BIG_SMEM, stream>>>(zA, wE2, enc_b2, zB, nullptr, nullptr, nullptr, M, 512, 512);
  gemm_big<1><<<g512, blk, BIG_SMEM, stream>>>(zB, wE3, enc_b3, zA, nullptr, nullptr, nullptr, M, 512, 512);

  // latent layers
  u16* cur = zA;
  u16* nxt = zB;
  for (int l = 0; l < 4; ++l) {
    norm_mlp2<<<256, dim3(256), 0, stream>>>(cur, mlp1_w + l * 1024, mlp1_b + l * 64,
                                             mlp2_w + l * 4096, mlp2_b + l * 64,
                                             mlp3_w + l * 1024, scales);
    gemm_big<2><<<g512, blk, BIG_SMEM, stream>>>(cur, wMix + (size_t)l * 262144, nullptr, nxt,
                                                 cur, scales, gate_b + l * 16, M, 512, 512);
    u16* t = cur; cur = nxt; nxt = t;
  }

  // decoder
  gemm_big<0><<<g512, blk, BIG_SMEM, stream>>>(cur, wD1, dec_b1, nxt, nullptr, nullptr, nullptr, M, 512, 512);
  { u16* t = cur; cur = nxt; nxt = t; }
  gemm_big<0><<<g512, blk, BIG_SMEM, stream>>>(cur, wD2, dec_b2, nxt, nullptr, nullptr, nullptr, M, 512, 512);
  { u16* t = cur; cur = nxt; nxt = t; }
  gemm_big<3><<<g1024, blk, BIG_SMEM, stream>>>(cur, wD3, dec_b3, d_out, nullptr, nullptr, nullptr, M, 1024, 512);
}